// Round 1
// baseline (674.263 us; speedup 1.0000x reference)
//
#include <hip/hip_runtime.h>

#define BB 128
#define TT 512
#define NN 200
#define START_IDX 1
#define END_IDX 2

#define NT 256     // threads per block
#define CI 8       // lanes per i-chunk group (c = lane & 7)
#define QI 28      // i's per thread
#define RJ 7       // j-rows per thread
#define ISLOTS 224 // 8*28
#define JSLOTS 224 // 7*32

__device__ __forceinline__ float dpp_add8(float x) {
  int v;
  v = __builtin_amdgcn_mov_dpp(__float_as_int(x), 0xB1, 0xF, 0xF, true);  // quad_perm [1,0,3,2] : xor1
  x += __int_as_float(v);
  v = __builtin_amdgcn_mov_dpp(__float_as_int(x), 0x4E, 0xF, 0xF, true);  // quad_perm [2,3,0,1] : xor2
  x += __int_as_float(v);
  v = __builtin_amdgcn_mov_dpp(__float_as_int(x), 0x141, 0xF, 0xF, true); // row_half_mirror : pairs quads in 8-group
  x += __int_as_float(v);
  return x;
}

__device__ __forceinline__ float max8(const float* w) {
  float4 a = *reinterpret_cast<const float4*>(w);
  float4 b = *reinterpret_cast<const float4*>(w + 4);
  return fmaxf(fmaxf(fmaxf(a.x, a.y), fmaxf(a.z, a.w)),
               fmaxf(fmaxf(b.x, b.y), fmaxf(b.z, b.w)));
}

__global__ __launch_bounds__(NT, 1) void crf_fwd_kernel(
    const float* __restrict__ unary, const int* __restrict__ tags,
    const int* __restrict__ lengths, const float* __restrict__ trans,
    float* __restrict__ ws) {
  const int b = blockIdx.x;
  const int tid = threadIdx.x;
  const int lane = tid & 63;
  const int wave = tid >> 6;
  const int c = lane & 7;               // i-chunk owner
  const int jg = (wave << 3) + (lane >> 3); // 0..31
  const bool lead = (c == 0);
  const int len = lengths[b];

  __shared__ __align__(16) float pL[ISLOTS];
  __shared__ __align__(16) float aL[JSLOTS];
  __shared__ __align__(16) float whm[2][8];
  __shared__ float red[8];
  __shared__ float goldS;

  const float* up = unary + (size_t)b * (TT * NN);

  // ---- init LDS: p = exp(alpha0 - 0) = 1 at START, 0 elsewhere; pad [200..223] = 0
  if (tid < ISLOTS) pL[tid] = (tid == START_IDX) ? 1.0f : 0.0f;
  if (tid < 8) { whm[0][tid] = 0.0f; whm[1][tid] = 0.0f; }

  // ---- load E = exp(trans) into registers: E[r][q] = exp(trans[r*32+jg][c*28+q])
  float E[RJ][QI];
#pragma unroll
  for (int r = 0; r < RJ; ++r) {
    const int j = r * 32 + jg;
    if (j < NN) {
      if (c < 7) {
        const float4* t4 = reinterpret_cast<const float4*>(trans + j * NN + c * QI);
#pragma unroll
        for (int k = 0; k < 7; ++k) {
          float4 tv = t4[k];
          E[r][4 * k + 0] = __expf(tv.x);
          E[r][4 * k + 1] = __expf(tv.y);
          E[r][4 * k + 2] = __expf(tv.z);
          E[r][4 * k + 3] = __expf(tv.w);
        }
      } else {
#pragma unroll
        for (int q = 0; q < QI; ++q) {
          const int i = c * QI + q;
          E[r][q] = (i < NN) ? __expf(trans[j * NN + i]) : 0.0f;
        }
      }
    } else {
#pragma unroll
      for (int q = 0; q < QI; ++q) E[r][q] = 0.0f;
    }
  }

  // ---- gold path score (cheap, thread-parallel over t)
  float g = 0.0f;
  for (int t = tid; t < len; t += NT) {
    const int cur = tags[b * TT + t];
    const int prev = (t == 0) ? START_IDX : tags[b * TT + t - 1];
    g += trans[cur * NN + prev] + up[(size_t)t * NN + cur];
  }
#pragma unroll
  for (int k = 32; k >= 1; k >>= 1) g += __shfl_xor(g, k, 64);
  if (lane == 0) red[wave] = g;
  __syncthreads();
  if (tid == 0) {
    const int lt = tags[b * TT + len - 1];
    goldS = red[0] + red[1] + red[2] + red[3] + trans[END_IDX * NN + lt];
  }

  // ---- prefetch u for t=0 (lead lanes own j-rows)
  float unext[RJ];
  if (lead) {
#pragma unroll
    for (int r = 0; r < RJ; ++r) {
      const int j = r * 32 + jg;
      unext[r] = (j < NN) ? up[j] : 0.0f;
    }
  }
  __syncthreads(); // init + gold visible

  // ---- main sequential scan
  for (int t = 0; t < len; ++t) {
    float ucur[RJ];
#pragma unroll
    for (int r = 0; r < RJ; ++r) ucur[r] = unext[r];
    if (lead && (t + 1) < len) {
#pragma unroll
      for (int r = 0; r < RJ; ++r) {
        const int j = r * 32 + jg;
        unext[r] = (j < NN) ? up[(size_t)(t + 1) * NN + j] : 0.0f;
      }
    }

    // FMA phase: S[j] = sum_i E[j,i] * p[i]
    float acc[RJ];
#pragma unroll
    for (int r = 0; r < RJ; ++r) acc[r] = 0.0f;
    const float4* p4 = reinterpret_cast<const float4*>(pL + c * QI);
#pragma unroll
    for (int k = 0; k < 7; ++k) {
      const float4 pv = p4[k];
#pragma unroll
      for (int r = 0; r < RJ; ++r) {
        acc[r] = fmaf(E[r][4 * k + 0], pv.x, acc[r]);
        acc[r] = fmaf(E[r][4 * k + 1], pv.y, acc[r]);
        acc[r] = fmaf(E[r][4 * k + 2], pv.z, acc[r]);
        acc[r] = fmaf(E[r][4 * k + 3], pv.w, acc[r]);
      }
    }
    // 8-lane group sum (all lanes end with full sum)
#pragma unroll
    for (int r = 0; r < RJ; ++r) acc[r] = dpp_add8(acc[r]);

    // epilogue: a' = u + m + log(S)
    const float mold = max8(&whm[t & 1][0]);
    float lmax = -3e38f;
    float anew[RJ];
    if (lead) {
#pragma unroll
      for (int r = 0; r < RJ; ++r) {
        const int j = r * 32 + jg;
        const float a = ucur[r] + mold + __logf(acc[r]);
        anew[r] = a;
        if (j < NN) lmax = fmaxf(lmax, a);
      }
    }
    // reduce lmax across the 4 lead lanes of each 32-lane half (full-exec swizzles)
    {
      int v;
      v = __builtin_amdgcn_ds_swizzle(__float_as_int(lmax), 0x201F); // xor 8
      lmax = fmaxf(lmax, __int_as_float(v));
      v = __builtin_amdgcn_ds_swizzle(__float_as_int(lmax), 0x401F); // xor 16
      lmax = fmaxf(lmax, __int_as_float(v));
    }
    if (lead) {
#pragma unroll
      for (int r = 0; r < RJ; ++r) {
        const int j = r * 32 + jg;
        if (j < NN) aL[j] = anew[r];
      }
    }
    if ((lane & 31) == 0) whm[(t + 1) & 1][(wave << 1) + (lane >> 5)] = lmax;
    __syncthreads(); // A: alpha + whm(new) ready

    // p phase: p = exp(alpha - m_new)
    if (tid < NN) {
      const float mnew = max8(&whm[(t + 1) & 1][0]);
      pL[tid] = __expf(aL[tid] - mnew);
    }
    __syncthreads(); // B: p ready
  }

  // ---- terminal: fwd = logsumexp_j(alpha[j] + trans[END, j])
  const float v = (tid < NN) ? (aL[tid] + trans[END_IDX * NN + tid]) : -3e38f;
  float mm = v;
#pragma unroll
  for (int k = 32; k >= 1; k >>= 1) mm = fmaxf(mm, __shfl_xor(mm, k, 64));
  if (lane == 0) red[wave] = mm;
  __syncthreads();
  mm = fmaxf(fmaxf(red[0], red[1]), fmaxf(red[2], red[3]));
  float e = (tid < NN) ? __expf(v - mm) : 0.0f;
#pragma unroll
  for (int k = 32; k >= 1; k >>= 1) e += __shfl_xor(e, k, 64);
  if (lane == 0) red[4 + wave] = e;
  __syncthreads();
  if (tid == 0) {
    const float fwd = mm + __logf(red[4] + red[5] + red[6] + red[7]);
    ws[b] = fwd - goldS;
  }
}

__global__ void crf_reduce_kernel(const float* __restrict__ wsIn,
                                  float* __restrict__ out) {
  const int tid = threadIdx.x; // 128 threads
  float v = wsIn[tid];
#pragma unroll
  for (int k = 32; k >= 1; k >>= 1) v += __shfl_xor(v, k, 64);
  __shared__ float s2[2];
  if ((tid & 63) == 0) s2[tid >> 6] = v;
  __syncthreads();
  if (tid == 0) out[0] = (s2[0] + s2[1]) * (1.0f / 128.0f);
}

extern "C" void kernel_launch(void* const* d_in, const int* in_sizes, int n_in,
                              void* d_out, int out_size, void* d_ws, size_t ws_size,
                              hipStream_t stream) {
  const float* unary = (const float*)d_in[0];
  const int* tags = (const int*)d_in[1];
  const int* lengths = (const int*)d_in[2];
  const float* trans = (const float*)d_in[3];
  float* ws = (float*)d_ws;
  float* out = (float*)d_out;

  crf_fwd_kernel<<<BB, NT, 0, stream>>>(unary, tags, lengths, trans, ws);
  crf_reduce_kernel<<<1, 128, 0, stream>>>(ws, out);
}

// Round 2
// 379.053 us; speedup vs baseline: 1.7788x; 1.7788x over previous
//
#include <hip/hip_runtime.h>

typedef float v2f __attribute__((ext_vector_type(2)));

#define BB 128
#define TT 512
#define NN 200
#define START_IDX 1
#define END_IDX 2

#define NT 512     // threads per block (8 waves)
#define QI 28      // i's per chunk (8 chunks: c = lane&7)
#define RJ 4       // j-rows per group (j = r*64 + jg, jg in [0,64))
#define ISLOTS 224 // padded p vector (200 -> 224)

__device__ __forceinline__ float dpp_add8(float x) {
  int v;
  v = __builtin_amdgcn_mov_dpp(__float_as_int(x), 0xB1, 0xF, 0xF, true);  // xor1 (quad_perm)
  x += __int_as_float(v);
  v = __builtin_amdgcn_mov_dpp(__float_as_int(x), 0x4E, 0xF, 0xF, true);  // xor2 (quad_perm)
  x += __int_as_float(v);
  v = __builtin_amdgcn_mov_dpp(__float_as_int(x), 0x141, 0xF, 0xF, true); // row_half_mirror
  x += __int_as_float(v);
  return x;
}

__device__ __forceinline__ float dpp_max8(float x) {
  int v;
  v = __builtin_amdgcn_mov_dpp(__float_as_int(x), 0xB1, 0xF, 0xF, true);
  x = fmaxf(x, __int_as_float(v));
  v = __builtin_amdgcn_mov_dpp(__float_as_int(x), 0x4E, 0xF, 0xF, true);
  x = fmaxf(x, __int_as_float(v));
  v = __builtin_amdgcn_mov_dpp(__float_as_int(x), 0x141, 0xF, 0xF, true);
  x = fmaxf(x, __int_as_float(v));
  return x;
}

__device__ __forceinline__ float wave_max(float x) {
  x = dpp_max8(x);
  x = fmaxf(x, __int_as_float(__builtin_amdgcn_ds_swizzle(__float_as_int(x), 0x201F))); // xor 8
  x = fmaxf(x, __int_as_float(__builtin_amdgcn_ds_swizzle(__float_as_int(x), 0x401F))); // xor 16
  x = fmaxf(x, __shfl_xor(x, 32, 64));                                                  // cross-half
  return x;
}

__global__ __launch_bounds__(NT, 2) void crf_fwd_kernel(
    const float* __restrict__ unary, const int* __restrict__ tags,
    const int* __restrict__ lengths, const float* __restrict__ trans,
    float* __restrict__ ws) {
  const int b = blockIdx.x;
  const int tid = threadIdx.x;
  const int lane = tid & 63;
  const int wave = tid >> 6;
  const int c = lane & 7;                   // i-chunk owner: i in [c*28, c*28+28)
  const int jg = (wave << 3) + (lane >> 3); // j-group, [0,64)
  const int len = lengths[b];

  __shared__ __align__(16) float pL[2][ISLOTS];
  __shared__ __align__(16) float whm[2][8];
  __shared__ float red[8];
  __shared__ float redE[8];
  __shared__ float goldS;

  const float* up = unary + (size_t)b * (TT * NN);

  // ---- init: p0 = exp(alpha0 - 0): 1 at START, 0 elsewhere; both buffers' pads = 0
  if (tid < ISLOTS) {
    pL[0][tid] = (tid == START_IDX) ? 1.0f : 0.0f;
    pL[1][tid] = 0.0f;
  }
  if (tid < 8) { whm[0][tid] = 0.0f; whm[1][tid] = 0.0f; } // max(alpha0) = 0

  // ---- E = exp(trans) register-resident, packed float2:
  // E2[r][k2] covers i = c*28 + 2*k2 .. +1 for row j = r*64 + jg
  v2f E2[RJ][QI / 2];
#pragma unroll
  for (int r = 0; r < RJ; ++r) {
    const int j = r * 64 + jg;
    if (j < NN) {
      if (c < 7) {
        const float4* t4 = reinterpret_cast<const float4*>(trans + j * NN + c * QI);
#pragma unroll
        for (int k = 0; k < 7; ++k) {
          const float4 tv = t4[k];
          E2[r][2 * k + 0] = v2f{__expf(tv.x), __expf(tv.y)};
          E2[r][2 * k + 1] = v2f{__expf(tv.z), __expf(tv.w)};
        }
      } else { // c == 7: i = 196..223, only 196..199 valid
        const float4 tv = *reinterpret_cast<const float4*>(trans + j * NN + 196);
        E2[r][0] = v2f{__expf(tv.x), __expf(tv.y)};
        E2[r][1] = v2f{__expf(tv.z), __expf(tv.w)};
#pragma unroll
        for (int k2 = 2; k2 < QI / 2; ++k2) E2[r][k2] = v2f{0.f, 0.f};
      }
    } else {
#pragma unroll
      for (int k2 = 0; k2 < QI / 2; ++k2) E2[r][k2] = v2f{0.f, 0.f};
    }
  }

  // ---- gold path score (one t per thread; len <= 512)
  float g = 0.0f;
  if (tid < len) {
    const int cur = tags[b * TT + tid];
    const int prev = (tid == 0) ? START_IDX : tags[b * TT + tid - 1];
    g = trans[cur * NN + prev] + up[(size_t)tid * NN + cur];
  }
#pragma unroll
  for (int k = 32; k >= 1; k >>= 1) g += __shfl_xor(g, k, 64);
  if (lane == 0) red[wave] = g;
  __syncthreads();
  if (tid == 0) {
    const int lt = tags[b * TT + len - 1];
    float gs = red[0];
#pragma unroll
    for (int w = 1; w < 8; ++w) gs += red[w];
    goldS = gs + trans[END_IDX * NN + lt];
  }

  // ---- epilogue row ownership: lane c (c<4) of each group handles j = c*64 + jg
  const int jrow = (c & 3) * 64 + jg;
  const bool erow = (c < 4) && (jrow < NN);
  float unext = 0.0f;
  if (erow) unext = up[jrow]; // u for t = 0
  __syncthreads(); // init + gold visible

  // ---- main scan: one barrier per step
  float A = 0.0f; // scale baked into current pL
  for (int t = 0; t < len; ++t) {
    const int rb = t & 1, wb = rb ^ 1;

    // issue the scale-array read early (latency hides under FMA phase)
    const float4 w0 = *reinterpret_cast<const float4*>(&whm[rb][0]);
    const float4 w1 = *reinterpret_cast<const float4*>(&whm[rb][4]);

    // S[j] = sum_i E[j,i] * p[i]  (packed fp32 FMA)
    v2f acc2[RJ];
#pragma unroll
    for (int r = 0; r < RJ; ++r) acc2[r] = v2f{0.f, 0.f};
    const float4* p4 = reinterpret_cast<const float4*>(&pL[rb][c * QI]);
#pragma unroll
    for (int k = 0; k < 7; ++k) {
      const float4 pv = p4[k];
      const v2f plo = v2f{pv.x, pv.y};
      const v2f phi = v2f{pv.z, pv.w};
#pragma unroll
      for (int r = 0; r < RJ; ++r) {
        acc2[r] = __builtin_elementwise_fma(E2[r][2 * k + 0], plo, acc2[r]);
        acc2[r] = __builtin_elementwise_fma(E2[r][2 * k + 1], phi, acc2[r]);
      }
    }

    const float B = fmaxf(fmaxf(fmaxf(w0.x, w0.y), fmaxf(w0.z, w0.w)),
                          fmaxf(fmaxf(w1.x, w1.y), fmaxf(w1.z, w1.w))); // max(alpha_t)

    float acc[RJ];
#pragma unroll
    for (int r = 0; r < RJ; ++r) acc[r] = dpp_add8(acc2[r].x + acc2[r].y);

    const float ucur = unext;
    if (erow && (t + 1) < len) unext = up[(size_t)(t + 1) * NN + jrow];

    // lane c<4 takes row r=c of its group
    float s = acc[0];
    s = (c == 1) ? acc[1] : s;
    s = (c == 2) ? acc[2] : s;
    s = (c == 3) ? acc[3] : s;

    const float anew = ucur + A + __logf(s); // alpha_{t+1}[jrow] (valid on erow lanes)
    float wmx = erow ? anew : -3e38f;
    wmx = wave_max(wmx);

    if (erow) pL[wb][jrow] = __expf(anew - B); // rescale with max(alpha_t): drift bounded
    if (lane == 0) whm[wb][wave] = wmx;        // partial maxes of alpha_{t+1}
    A = B;
    __syncthreads();
  }

  // ---- terminal: fwd = logsumexp_j(alpha[j] + trans[END, j]), alpha = A + log(p)
  const int fb = len & 1;
  float v = -3e38f;
  if (tid < NN) v = A + __logf(pL[fb][tid]) + trans[END_IDX * NN + tid];
  float mm = v;
#pragma unroll
  for (int k = 32; k >= 1; k >>= 1) mm = fmaxf(mm, __shfl_xor(mm, k, 64));
  if (lane == 0) red[wave] = mm;
  __syncthreads();
  mm = red[0];
#pragma unroll
  for (int w = 1; w < 8; ++w) mm = fmaxf(mm, red[w]);
  float e = (tid < NN) ? __expf(v - mm) : 0.0f;
#pragma unroll
  for (int k = 32; k >= 1; k >>= 1) e += __shfl_xor(e, k, 64);
  if (lane == 0) redE[wave] = e;
  __syncthreads();
  if (tid == 0) {
    float es = redE[0];
#pragma unroll
    for (int w = 1; w < 8; ++w) es += redE[w];
    ws[b] = (mm + __logf(es)) - goldS;
  }
}

__global__ void crf_reduce_kernel(const float* __restrict__ wsIn,
                                  float* __restrict__ out) {
  const int tid = threadIdx.x; // 128 threads
  float v = wsIn[tid];
#pragma unroll
  for (int k = 32; k >= 1; k >>= 1) v += __shfl_xor(v, k, 64);
  __shared__ float s2[2];
  if ((tid & 63) == 0) s2[tid >> 6] = v;
  __syncthreads();
  if (tid == 0) out[0] = (s2[0] + s2[1]) * (1.0f / 128.0f);
}

extern "C" void kernel_launch(void* const* d_in, const int* in_sizes, int n_in,
                              void* d_out, int out_size, void* d_ws, size_t ws_size,
                              hipStream_t stream) {
  const float* unary = (const float*)d_in[0];
  const int* tags = (const int*)d_in[1];
  const int* lengths = (const int*)d_in[2];
  const float* trans = (const float*)d_in[3];
  float* ws = (float*)d_ws;
  float* out = (float*)d_out;

  crf_fwd_kernel<<<BB, NT, 0, stream>>>(unary, tags, lengths, trans, ws);
  crf_reduce_kernel<<<1, 128, 0, stream>>>(ws, out);
}

// Round 3
// 344.341 us; speedup vs baseline: 1.9581x; 1.1008x over previous
//
#include <hip/hip_runtime.h>

typedef float v2f __attribute__((ext_vector_type(2)));

#define BB 128
#define TT 512
#define NN 200
#define START_IDX 1
#define END_IDX 2

#define NT 512     // 8 waves
#define QI 28      // i's per chunk, chunk owner c = lane&7
#define ISLOTS 224 // padded p vector

// sum over 8-lane group (lanes with same lane>>3); all 8 lanes get the sum
__device__ __forceinline__ float dpp_add8(float x) {
  int v;
  v = __builtin_amdgcn_mov_dpp(__float_as_int(x), 0xB1, 0xF, 0xF, true);  // quad xor1
  x += __int_as_float(v);
  v = __builtin_amdgcn_mov_dpp(__float_as_int(x), 0x4E, 0xF, 0xF, true);  // quad xor2
  x += __int_as_float(v);
  v = __builtin_amdgcn_mov_dpp(__float_as_int(x), 0x141, 0xF, 0xF, true); // row_half_mirror
  x += __int_as_float(v);
  return x;
}

// full-wave max, pure DPP (no LDS pipe). Result valid in lane 63.
__device__ __forceinline__ float wave_max_dpp(float x) {
  int v;
  v = __builtin_amdgcn_mov_dpp(__float_as_int(x), 0xB1, 0xF, 0xF, true);
  x = fmaxf(x, __int_as_float(v));
  v = __builtin_amdgcn_mov_dpp(__float_as_int(x), 0x4E, 0xF, 0xF, true);
  x = fmaxf(x, __int_as_float(v));
  v = __builtin_amdgcn_mov_dpp(__float_as_int(x), 0x141, 0xF, 0xF, true); // 8
  x = fmaxf(x, __int_as_float(v));
  v = __builtin_amdgcn_mov_dpp(__float_as_int(x), 0x140, 0xF, 0xF, true); // row_mirror: 16
  x = fmaxf(x, __int_as_float(v));
  v = __builtin_amdgcn_mov_dpp(__float_as_int(x), 0x142, 0xF, 0xF, true); // bcast15: 32
  x = fmaxf(x, __int_as_float(v));
  v = __builtin_amdgcn_mov_dpp(__float_as_int(x), 0x143, 0xF, 0xF, true); // bcast31: 64
  x = fmaxf(x, __int_as_float(v));
  return x;
}

__device__ __forceinline__ float max8f(float4 a, float4 b) {
  return fmaxf(fmaxf(fmaxf(a.x, a.y), fmaxf(a.z, a.w)),
               fmaxf(fmaxf(b.x, b.y), fmaxf(b.z, b.w)));
}

__global__ __launch_bounds__(NT, 2) void crf_fwd_kernel(
    const float* __restrict__ unary, const int* __restrict__ tags,
    const int* __restrict__ lengths, const float* __restrict__ trans,
    float* __restrict__ ws) {
  const int b = blockIdx.x;
  const int tid = threadIdx.x;
  const int lane = tid & 63;
  const int wave = tid >> 6;
  const int c = lane & 7;                   // i-chunk: i in [c*28, c*28+28)
  const int jg = (wave << 3) + (lane >> 3); // group id, [0,64)
  const bool W7 = (wave == 7);
  const int len = lengths[b];

  __shared__ __align__(16) float pL[2][ISLOTS];
  __shared__ __align__(16) float whm[2][8];
  __shared__ float red[8];
  __shared__ float redE[8];
  __shared__ float goldS;

  const float* up = unary + (size_t)b * (TT * NN);

  // ---- init: p0 = exp(alpha0): 1 at START, 0 elsewhere; pads stay 0 forever
  if (tid < ISLOTS) {
    pL[0][tid] = (tid == START_IDX) ? 1.0f : 0.0f;
    pL[1][tid] = 0.0f;
  }
  if (tid < 8) { whm[0][tid] = 1.0f; whm[1][tid] = 0.0f; } // max(p0)=1

  // ---- E = exp(trans): group jg owns rows j = 3*jg + r (r<3) -> rows 0..191;
  //      wave 7 groups additionally own row 136+jg -> rows 192..199.
  v2f E2[3][QI / 2];
  v2f EX[QI / 2];
#pragma unroll
  for (int k2 = 0; k2 < QI / 2; ++k2) EX[k2] = v2f{0.f, 0.f};
#pragma unroll
  for (int r = 0; r < 3; ++r) {
    const int j = 3 * jg + r; // < 192 always
    if (c < 7) {
      const float4* t4 = reinterpret_cast<const float4*>(trans + j * NN + c * QI);
#pragma unroll
      for (int k = 0; k < 7; ++k) {
        const float4 tv = t4[k];
        E2[r][2 * k + 0] = v2f{__expf(tv.x), __expf(tv.y)};
        E2[r][2 * k + 1] = v2f{__expf(tv.z), __expf(tv.w)};
      }
    } else { // i = 196..199 valid only
      const float4 tv = *reinterpret_cast<const float4*>(trans + j * NN + 196);
      E2[r][0] = v2f{__expf(tv.x), __expf(tv.y)};
      E2[r][1] = v2f{__expf(tv.z), __expf(tv.w)};
#pragma unroll
      for (int k2 = 2; k2 < QI / 2; ++k2) E2[r][k2] = v2f{0.f, 0.f};
    }
  }
  if (W7) {
    const int j = 136 + jg; // 192..199
    if (c < 7) {
      const float4* t4 = reinterpret_cast<const float4*>(trans + j * NN + c * QI);
#pragma unroll
      for (int k = 0; k < 7; ++k) {
        const float4 tv = t4[k];
        EX[2 * k + 0] = v2f{__expf(tv.x), __expf(tv.y)};
        EX[2 * k + 1] = v2f{__expf(tv.z), __expf(tv.w)};
      }
    } else {
      const float4 tv = *reinterpret_cast<const float4*>(trans + j * NN + 196);
      EX[0] = v2f{__expf(tv.x), __expf(tv.y)};
      EX[1] = v2f{__expf(tv.z), __expf(tv.w)};
    }
  }

  // ---- gold path score (one t per thread)
  float g = 0.0f;
  if (tid < len) {
    const int cur = tags[b * TT + tid];
    const int prev = (tid == 0) ? START_IDX : tags[b * TT + tid - 1];
    g = trans[cur * NN + prev] + up[(size_t)tid * NN + cur];
  }
#pragma unroll
  for (int k = 32; k >= 1; k >>= 1) g += __shfl_xor(g, k, 64);
  if (lane == 0) red[wave] = g;
  __syncthreads();
  if (tid == 0) {
    const int lt = tags[b * TT + len - 1];
    float gs = red[0];
#pragma unroll
    for (int w = 1; w < 8; ++w) gs += red[w];
    goldS = gs + trans[END_IDX * NN + lt];
  }

  // ---- epilogue ownership: lane c<3 -> row 3*jg+c; wave7 lane c==3 -> row 136+jg
  const bool erow = (c < 3) || (W7 && (c == 3));
  const int jrow = (c < 3) ? (3 * jg + c) : (136 + jg);

  // u pipeline: loads 3 ahead, exp 1 ahead
  float uexpC = 0.f, uA = 0.f, uB = 0.f;
  if (erow) {
    uexpC = __expf(up[jrow]);                                   // exp(u_0)
    uA = up[(size_t)((1 < len) ? 1 : len - 1) * NN + jrow];     // u_1
    uB = up[(size_t)((2 < len) ? 2 : len - 1) * NN + jrow];     // u_2
  }
  float A = 0.0f; // running scale: A_t = max(alpha_{t-1})
  __syncthreads();

  // ---- main scan: one barrier per step, no transcendental/LDS-swizzle on chain
  for (int t = 0; t < len; ++t) {
    const int rb = t & 1, wb = rb ^ 1;

    // off-path: M_t, 1/M_t, A accumulation (feeds pnew ~200cyc later)
    const float4 w0 = *reinterpret_cast<const float4*>(&whm[rb][0]);
    const float4 w1 = *reinterpret_cast<const float4*>(&whm[rb][4]);
    const float M = max8f(w0, w1);
    const float rcpM = __builtin_amdgcn_rcpf(M);
    A += __logf(M);

    // off-path: u pipeline
    float L = 0.f;
    if (erow) {
      const int ti = (t + 3 < len) ? (t + 3) : (len - 1);
      L = up[(size_t)ti * NN + jrow];
    }
    const float uexpN = erow ? __expf(uA) : 0.f;
    const float f = uexpC * rcpM;

    // critical path: S = E * p
    v2f a0 = {0.f, 0.f}, a1 = {0.f, 0.f}, a2 = {0.f, 0.f}, aX = {0.f, 0.f};
    const float4* p4 = reinterpret_cast<const float4*>(&pL[rb][c * QI]);
#pragma unroll
    for (int k = 0; k < 7; ++k) {
      const float4 pv = p4[k];
      const v2f plo = v2f{pv.x, pv.y};
      const v2f phi = v2f{pv.z, pv.w};
      a0 = __builtin_elementwise_fma(E2[0][2 * k + 0], plo, a0);
      a0 = __builtin_elementwise_fma(E2[0][2 * k + 1], phi, a0);
      a1 = __builtin_elementwise_fma(E2[1][2 * k + 0], plo, a1);
      a1 = __builtin_elementwise_fma(E2[1][2 * k + 1], phi, a1);
      a2 = __builtin_elementwise_fma(E2[2][2 * k + 0], plo, a2);
      a2 = __builtin_elementwise_fma(E2[2][2 * k + 1], phi, a2);
      if (W7) {
        aX = __builtin_elementwise_fma(EX[2 * k + 0], plo, aX);
        aX = __builtin_elementwise_fma(EX[2 * k + 1], phi, aX);
      }
    }
    const float s0 = dpp_add8(a0.x + a0.y);
    const float s1 = dpp_add8(a1.x + a1.y);
    const float s2 = dpp_add8(a2.x + a2.y);
    float s = s0;
    s = (c == 1) ? s1 : s;
    s = (c == 2) ? s2 : s;
    if (W7) {
      const float sX = dpp_add8(aX.x + aX.y);
      s = (c == 3) ? sX : s;
    }

    // p_new = S * exp(u)/M_t   (exact: alpha never materialized)
    const float pnew = s * f;
    float mx = erow ? pnew : 0.f;
    mx = wave_max_dpp(mx); // lane 63 valid
    if (erow) pL[wb][jrow] = pnew;
    if (lane == 63) whm[wb][wave] = mx;

    uexpC = uexpN; uA = uB; uB = L;
    __syncthreads();
  }

  // ---- terminal: alpha = A + log(p); logsumexp_j(alpha + trans[END,j])
  const int fb = len & 1;
  float v = -3e38f;
  if (tid < NN) v = A + __logf(pL[fb][tid]) + trans[END_IDX * NN + tid];
  float mm = v;
#pragma unroll
  for (int k = 32; k >= 1; k >>= 1) mm = fmaxf(mm, __shfl_xor(mm, k, 64));
  if (lane == 0) red[wave] = mm;
  __syncthreads();
  mm = red[0];
#pragma unroll
  for (int w = 1; w < 8; ++w) mm = fmaxf(mm, red[w]);
  float e = (tid < NN) ? __expf(v - mm) : 0.0f;
#pragma unroll
  for (int k = 32; k >= 1; k >>= 1) e += __shfl_xor(e, k, 64);
  if (lane == 0) redE[wave] = e;
  __syncthreads();
  if (tid == 0) {
    float es = redE[0];
#pragma unroll
    for (int w = 1; w < 8; ++w) es += redE[w];
    ws[b] = (mm + __logf(es)) - goldS;
  }
}

__global__ void crf_reduce_kernel(const float* __restrict__ wsIn,
                                  float* __restrict__ out) {
  const int tid = threadIdx.x; // 128 threads
  float v = wsIn[tid];
#pragma unroll
  for (int k = 32; k >= 1; k >>= 1) v += __shfl_xor(v, k, 64);
  __shared__ float s2[2];
  if ((tid & 63) == 0) s2[tid >> 6] = v;
  __syncthreads();
  if (tid == 0) out[0] = (s2[0] + s2[1]) * (1.0f / 128.0f);
}

extern "C" void kernel_launch(void* const* d_in, const int* in_sizes, int n_in,
                              void* d_out, int out_size, void* d_ws, size_t ws_size,
                              hipStream_t stream) {
  const float* unary = (const float*)d_in[0];
  const int* tags = (const int*)d_in[1];
  const int* lengths = (const int*)d_in[2];
  const float* trans = (const float*)d_in[3];
  float* ws = (float*)d_ws;
  float* out = (float*)d_out;

  crf_fwd_kernel<<<BB, NT, 0, stream>>>(unary, tags, lengths, trans, ws);
  crf_reduce_kernel<<<1, 128, 0, stream>>>(ws, out);
}

// Round 4
// 343.352 us; speedup vs baseline: 1.9638x; 1.0029x over previous
//
#include <hip/hip_runtime.h>

typedef float v2f __attribute__((ext_vector_type(2)));

#define BB 128
#define TT 512
#define NN 200
#define START_IDX 1
#define END_IDX 2

#define NT 512     // 8 waves
#define QI 28      // i's per chunk, chunk owner c = lane&7
#define ISLOTS 224 // padded p vector

// sum over 8-lane group (lanes with same lane>>3); all 8 lanes get the sum
__device__ __forceinline__ float dpp_add8(float x) {
  int v;
  v = __builtin_amdgcn_mov_dpp(__float_as_int(x), 0xB1, 0xF, 0xF, true);  // quad xor1
  x += __int_as_float(v);
  v = __builtin_amdgcn_mov_dpp(__float_as_int(x), 0x4E, 0xF, 0xF, true);  // quad xor2
  x += __int_as_float(v);
  v = __builtin_amdgcn_mov_dpp(__float_as_int(x), 0x141, 0xF, 0xF, true); // row_half_mirror
  x += __int_as_float(v);
  return x;
}

// full-wave max, pure DPP (no LDS pipe). Result valid in lane 63.
__device__ __forceinline__ float wave_max_dpp(float x) {
  int v;
  v = __builtin_amdgcn_mov_dpp(__float_as_int(x), 0xB1, 0xF, 0xF, true);
  x = fmaxf(x, __int_as_float(v));
  v = __builtin_amdgcn_mov_dpp(__float_as_int(x), 0x4E, 0xF, 0xF, true);
  x = fmaxf(x, __int_as_float(v));
  v = __builtin_amdgcn_mov_dpp(__float_as_int(x), 0x141, 0xF, 0xF, true); // 8
  x = fmaxf(x, __int_as_float(v));
  v = __builtin_amdgcn_mov_dpp(__float_as_int(x), 0x140, 0xF, 0xF, true); // row_mirror: 16
  x = fmaxf(x, __int_as_float(v));
  v = __builtin_amdgcn_mov_dpp(__float_as_int(x), 0x142, 0xF, 0xF, true); // bcast15: 32
  x = fmaxf(x, __int_as_float(v));
  v = __builtin_amdgcn_mov_dpp(__float_as_int(x), 0x143, 0xF, 0xF, true); // bcast31: 64
  x = fmaxf(x, __int_as_float(v));
  return x;
}

__device__ __forceinline__ float max8f(float4 a, float4 b) {
  return fmaxf(fmaxf(fmaxf(a.x, a.y), fmaxf(a.z, a.w)),
               fmaxf(fmaxf(b.x, b.y), fmaxf(b.z, b.w)));
}

// Pin occupancy to exactly what the 128-block grid provides (2 waves/EU) so the
// register allocator gets the full 256-VGPR budget and keeps E resident.
__global__ __attribute__((amdgpu_waves_per_eu(2, 2))) __launch_bounds__(NT)
void crf_fwd_kernel(
    const float* __restrict__ unary, const int* __restrict__ tags,
    const int* __restrict__ lengths, const float* __restrict__ trans,
    float* __restrict__ ws) {
  const int b = blockIdx.x;
  const int tid = threadIdx.x;
  const int lane = tid & 63;
  const int wave = tid >> 6;
  const int c = lane & 7;                   // i-chunk: i in [c*28, c*28+28)
  const int jg = (wave << 3) + (lane >> 3); // group id, [0,64)
  const bool W7 = (wave == 7);
  const int len = lengths[b];

  __shared__ __align__(16) float pL[2][ISLOTS];
  __shared__ __align__(16) float whm[2][8];
  __shared__ float red[8];
  __shared__ float redE[8];
  __shared__ float goldS;

  const float* up = unary + (size_t)b * (TT * NN);

  // ---- init: p0 = exp(alpha0): 1 at START, 0 elsewhere; pads stay 0 forever
  if (tid < ISLOTS) {
    pL[0][tid] = (tid == START_IDX) ? 1.0f : 0.0f;
    pL[1][tid] = 0.0f;
  }
  if (tid < 8) { whm[0][tid] = 1.0f; whm[1][tid] = 0.0f; } // max(p0)=1

  // ---- E = exp(trans): group jg owns rows j = 3*jg + r (r<3) -> rows 0..191;
  //      wave 7 groups additionally own row 136+jg -> rows 192..199.
  v2f E2[3][QI / 2];
  v2f EX[QI / 2];
#pragma unroll
  for (int k2 = 0; k2 < QI / 2; ++k2) EX[k2] = v2f{0.f, 0.f};
#pragma unroll
  for (int r = 0; r < 3; ++r) {
    const int j = 3 * jg + r; // < 192 always
    if (c < 7) {
      const float4* t4 = reinterpret_cast<const float4*>(trans + j * NN + c * QI);
#pragma unroll
      for (int k = 0; k < 7; ++k) {
        const float4 tv = t4[k];
        E2[r][2 * k + 0] = v2f{__expf(tv.x), __expf(tv.y)};
        E2[r][2 * k + 1] = v2f{__expf(tv.z), __expf(tv.w)};
      }
    } else { // i = 196..199 valid only
      const float4 tv = *reinterpret_cast<const float4*>(trans + j * NN + 196);
      E2[r][0] = v2f{__expf(tv.x), __expf(tv.y)};
      E2[r][1] = v2f{__expf(tv.z), __expf(tv.w)};
#pragma unroll
      for (int k2 = 2; k2 < QI / 2; ++k2) E2[r][k2] = v2f{0.f, 0.f};
    }
  }
  if (W7) {
    const int j = 136 + jg; // 192..199
    if (c < 7) {
      const float4* t4 = reinterpret_cast<const float4*>(trans + j * NN + c * QI);
#pragma unroll
      for (int k = 0; k < 7; ++k) {
        const float4 tv = t4[k];
        EX[2 * k + 0] = v2f{__expf(tv.x), __expf(tv.y)};
        EX[2 * k + 1] = v2f{__expf(tv.z), __expf(tv.w)};
      }
    } else {
      const float4 tv = *reinterpret_cast<const float4*>(trans + j * NN + 196);
      EX[0] = v2f{__expf(tv.x), __expf(tv.y)};
      EX[1] = v2f{__expf(tv.z), __expf(tv.w)};
    }
  }

  // ---- gold path score (one t per thread)
  float g = 0.0f;
  if (tid < len) {
    const int cur = tags[b * TT + tid];
    const int prev = (tid == 0) ? START_IDX : tags[b * TT + tid - 1];
    g = trans[cur * NN + prev] + up[(size_t)tid * NN + cur];
  }
#pragma unroll
  for (int k = 32; k >= 1; k >>= 1) g += __shfl_xor(g, k, 64);
  if (lane == 0) red[wave] = g;
  __syncthreads();
  if (tid == 0) {
    const int lt = tags[b * TT + len - 1];
    float gs = red[0];
#pragma unroll
    for (int w = 1; w < 8; ++w) gs += red[w];
    goldS = gs + trans[END_IDX * NN + lt];
  }

  // ---- epilogue ownership: lane c<3 -> row 3*jg+c; wave7 lane c==3 -> row 136+jg
  const bool erow = (c < 3) || (W7 && (c == 3));
  const int jrow = (c < 3) ? (3 * jg + c) : (136 + jg);

  // u pipeline: loads 3 ahead, exp 1 ahead
  float uexpC = 0.f, uA = 0.f, uB = 0.f;
  if (erow) {
    uexpC = __expf(up[jrow]);                                   // exp(u_0)
    uA = up[(size_t)((1 < len) ? 1 : len - 1) * NN + jrow];     // u_1
    uB = up[(size_t)((2 < len) ? 2 : len - 1) * NN + jrow];     // u_2
  }
  float A = 0.0f; // running scale: A_t = max(alpha_{t-1})
  __syncthreads();

  // ---- main scan: one barrier per step, no transcendental/LDS-swizzle on chain
  for (int t = 0; t < len; ++t) {
    const int rb = t & 1, wb = rb ^ 1;

    // off-path: M_t, 1/M_t, A accumulation (feeds pnew ~200cyc later)
    const float4 w0 = *reinterpret_cast<const float4*>(&whm[rb][0]);
    const float4 w1 = *reinterpret_cast<const float4*>(&whm[rb][4]);
    const float M = max8f(w0, w1);
    const float rcpM = __builtin_amdgcn_rcpf(M);
    A += __logf(M);

    // off-path: u pipeline
    float L = 0.f;
    if (erow) {
      const int ti = (t + 3 < len) ? (t + 3) : (len - 1);
      L = up[(size_t)ti * NN + jrow];
    }
    const float uexpN = erow ? __expf(uA) : 0.f;
    const float f = uexpC * rcpM;

    // critical path: S = E * p
    v2f a0 = {0.f, 0.f}, a1 = {0.f, 0.f}, a2 = {0.f, 0.f}, aX = {0.f, 0.f};
    const float4* p4 = reinterpret_cast<const float4*>(&pL[rb][c * QI]);
#pragma unroll
    for (int k = 0; k < 7; ++k) {
      const float4 pv = p4[k];
      const v2f plo = v2f{pv.x, pv.y};
      const v2f phi = v2f{pv.z, pv.w};
      a0 = __builtin_elementwise_fma(E2[0][2 * k + 0], plo, a0);
      a0 = __builtin_elementwise_fma(E2[0][2 * k + 1], phi, a0);
      a1 = __builtin_elementwise_fma(E2[1][2 * k + 0], plo, a1);
      a1 = __builtin_elementwise_fma(E2[1][2 * k + 1], phi, a1);
      a2 = __builtin_elementwise_fma(E2[2][2 * k + 0], plo, a2);
      a2 = __builtin_elementwise_fma(E2[2][2 * k + 1], phi, a2);
      if (W7) {
        aX = __builtin_elementwise_fma(EX[2 * k + 0], plo, aX);
        aX = __builtin_elementwise_fma(EX[2 * k + 1], phi, aX);
      }
    }
    const float s0 = dpp_add8(a0.x + a0.y);
    const float s1 = dpp_add8(a1.x + a1.y);
    const float s2 = dpp_add8(a2.x + a2.y);
    float s = s0;
    s = (c == 1) ? s1 : s;
    s = (c == 2) ? s2 : s;
    if (W7) {
      const float sX = dpp_add8(aX.x + aX.y);
      s = (c == 3) ? sX : s;
    }

    // p_new = S * exp(u)/M_t   (exact: alpha never materialized)
    const float pnew = s * f;
    float mx = erow ? pnew : 0.f;
    mx = wave_max_dpp(mx); // lane 63 valid
    if (erow) pL[wb][jrow] = pnew;
    if (lane == 63) whm[wb][wave] = mx;

    uexpC = uexpN; uA = uB; uB = L;
    __syncthreads();
  }

  // ---- terminal: alpha = A + log(p); logsumexp_j(alpha + trans[END,j])
  const int fb = len & 1;
  float v = -3e38f;
  if (tid < NN) v = A + __logf(pL[fb][tid]) + trans[END_IDX * NN + tid];
  float mm = v;
#pragma unroll
  for (int k = 32; k >= 1; k >>= 1) mm = fmaxf(mm, __shfl_xor(mm, k, 64));
  if (lane == 0) red[wave] = mm;
  __syncthreads();
  mm = red[0];
#pragma unroll
  for (int w = 1; w < 8; ++w) mm = fmaxf(mm, red[w]);
  float e = (tid < NN) ? __expf(v - mm) : 0.0f;
#pragma unroll
  for (int k = 32; k >= 1; k >>= 1) e += __shfl_xor(e, k, 64);
  if (lane == 0) redE[wave] = e;
  __syncthreads();
  if (tid == 0) {
    float es = redE[0];
#pragma unroll
    for (int w = 1; w < 8; ++w) es += redE[w];
    ws[b] = (mm + __logf(es)) - goldS;
  }
}

__global__ void crf_reduce_kernel(const float* __restrict__ wsIn,
                                  float* __restrict__ out) {
  const int tid = threadIdx.x; // 128 threads
  float v = wsIn[tid];
#pragma unroll
  for (int k = 32; k >= 1; k >>= 1) v += __shfl_xor(v, k, 64);
  __shared__ float s2[2];
  if ((tid & 63) == 0) s2[tid >> 6] = v;
  __syncthreads();
  if (tid == 0) out[0] = (s2[0] + s2[1]) * (1.0f / 128.0f);
}

extern "C" void kernel_launch(void* const* d_in, const int* in_sizes, int n_in,
                              void* d_out, int out_size, void* d_ws, size_t ws_size,
                              hipStream_t stream) {
  const float* unary = (const float*)d_in[0];
  const int* tags = (const int*)d_in[1];
  const int* lengths = (const int*)d_in[2];
  const float* trans = (const float*)d_in[3];
  float* ws = (float*)d_ws;
  float* out = (float*)d_out;

  crf_fwd_kernel<<<BB, NT, 0, stream>>>(unary, tags, lengths, trans, ws);
  crf_reduce_kernel<<<1, 128, 0, stream>>>(ws, out);
}

// Round 5
// 327.319 us; speedup vs baseline: 2.0600x; 1.0490x over previous
//
#include <hip/hip_runtime.h>

typedef _Float16 v2h __attribute__((ext_vector_type(2)));

#define BB 128
#define TT 512
#define NN 200
#define START_IDX 1
#define END_IDX 2

#define NT 512 // 8 waves
#define QI 28  // real i's per chunk (chunk owner c = lane&7)
#define CH 32  // padded halves per chunk (64-byte LDS stride)

#if __has_builtin(__builtin_amdgcn_fdot2)
__device__ __forceinline__ float fdot2(v2h a, v2h b, float c) {
  return __builtin_amdgcn_fdot2(a, b, c, false);
}
#else
__device__ __forceinline__ float fdot2(v2h a, v2h b, float c) {
  return c + (float)a.x * (float)b.x + (float)a.y * (float)b.y;
}
#endif

// sum over 8-lane group; all 8 lanes get the sum
__device__ __forceinline__ float dpp_add8(float x) {
  int v;
  v = __builtin_amdgcn_mov_dpp(__float_as_int(x), 0xB1, 0xF, 0xF, true);  // quad xor1
  x += __int_as_float(v);
  v = __builtin_amdgcn_mov_dpp(__float_as_int(x), 0x4E, 0xF, 0xF, true);  // quad xor2
  x += __int_as_float(v);
  v = __builtin_amdgcn_mov_dpp(__float_as_int(x), 0x141, 0xF, 0xF, true); // row_half_mirror
  x += __int_as_float(v);
  return x;
}

// full-wave max, pure DPP. Result valid in lane 63.
__device__ __forceinline__ float wave_max_dpp(float x) {
  int v;
  v = __builtin_amdgcn_mov_dpp(__float_as_int(x), 0xB1, 0xF, 0xF, true);
  x = fmaxf(x, __int_as_float(v));
  v = __builtin_amdgcn_mov_dpp(__float_as_int(x), 0x4E, 0xF, 0xF, true);
  x = fmaxf(x, __int_as_float(v));
  v = __builtin_amdgcn_mov_dpp(__float_as_int(x), 0x141, 0xF, 0xF, true); // 8
  x = fmaxf(x, __int_as_float(v));
  v = __builtin_amdgcn_mov_dpp(__float_as_int(x), 0x140, 0xF, 0xF, true); // row_mirror: 16
  x = fmaxf(x, __int_as_float(v));
  v = __builtin_amdgcn_mov_dpp(__float_as_int(x), 0x142, 0xF, 0xF, true); // bcast15: 32
  x = fmaxf(x, __int_as_float(v));
  v = __builtin_amdgcn_mov_dpp(__float_as_int(x), 0x143, 0xF, 0xF, true); // bcast31: 64
  x = fmaxf(x, __int_as_float(v));
  return x;
}

__device__ __forceinline__ float max8f(float4 a, float4 b) {
  return fmaxf(fmaxf(fmaxf(a.x, a.y), fmaxf(a.z, a.w)),
               fmaxf(fmaxf(b.x, b.y), fmaxf(b.z, b.w)));
}

__global__ __attribute__((amdgpu_flat_work_group_size(NT, NT),
                          amdgpu_waves_per_eu(2, 2)))
void crf_fwd_kernel(
    const float* __restrict__ unary, const int* __restrict__ tags,
    const int* __restrict__ lengths, const float* __restrict__ trans,
    float* __restrict__ ws) {
  const int b = blockIdx.x;
  const int tid = threadIdx.x;
  const int lane = tid & 63;
  const int wave = tid >> 6;
  const int c = lane & 7;                   // i-chunk: i in [c*28, c*28+28)
  const int jg = (wave << 3) + (lane >> 3); // group id, [0,64)
  const bool W7 = (wave == 7);
  const int len = lengths[b];

  __shared__ __align__(16) _Float16 pH[2][8 * CH]; // p in fp16, 64B chunk stride
  __shared__ __align__(16) float whm[2][8];
  __shared__ float red[8];
  __shared__ float redE[8];
  __shared__ float goldS;

  const float* up = unary + (size_t)b * (TT * NN);

  // ---- init: p0 = 1 at START (state 1 -> chunk 0 slot 1 -> half index 1), 0 else
  if (tid < 8 * CH) {
    pH[0][tid] = (tid == 1) ? (_Float16)1.0f : (_Float16)0.0f;
    pH[1][tid] = (_Float16)0.0f;
  }
  if (tid < 8) { whm[0][tid] = 1.0f; whm[1][tid] = 0.0f; } // max(p0)=1

  // ---- E = exp(trans) in fp16 pairs: group jg owns rows 3*jg+r (r<3);
  //      wave-7 groups additionally own row 136+jg (rows 192..199).
  v2h Er[3][QI / 2];
  v2h Ex[QI / 2];
#pragma unroll
  for (int k = 0; k < QI / 2; ++k) Ex[k] = v2h{(_Float16)0, (_Float16)0};
#pragma unroll
  for (int r = 0; r < 3; ++r) {
    const int j = 3 * jg + r; // < 192
    if (c < 7) {
      const float4* t4 = reinterpret_cast<const float4*>(trans + j * NN + c * QI);
#pragma unroll
      for (int k = 0; k < 7; ++k) {
        const float4 tv = t4[k];
        Er[r][2 * k + 0] = v2h{(_Float16)__expf(tv.x), (_Float16)__expf(tv.y)};
        Er[r][2 * k + 1] = v2h{(_Float16)__expf(tv.z), (_Float16)__expf(tv.w)};
      }
    } else { // only i = 196..199 valid
      const float4 tv = *reinterpret_cast<const float4*>(trans + j * NN + 196);
      Er[r][0] = v2h{(_Float16)__expf(tv.x), (_Float16)__expf(tv.y)};
      Er[r][1] = v2h{(_Float16)__expf(tv.z), (_Float16)__expf(tv.w)};
#pragma unroll
      for (int k = 2; k < QI / 2; ++k) Er[r][k] = v2h{(_Float16)0, (_Float16)0};
    }
  }
  if (W7) {
    const int j = 136 + jg; // 192..199
    if (c < 7) {
      const float4* t4 = reinterpret_cast<const float4*>(trans + j * NN + c * QI);
#pragma unroll
      for (int k = 0; k < 7; ++k) {
        const float4 tv = t4[k];
        Ex[2 * k + 0] = v2h{(_Float16)__expf(tv.x), (_Float16)__expf(tv.y)};
        Ex[2 * k + 1] = v2h{(_Float16)__expf(tv.z), (_Float16)__expf(tv.w)};
      }
    } else {
      const float4 tv = *reinterpret_cast<const float4*>(trans + j * NN + 196);
      Ex[0] = v2h{(_Float16)__expf(tv.x), (_Float16)__expf(tv.y)};
      Ex[1] = v2h{(_Float16)__expf(tv.z), (_Float16)__expf(tv.w)};
    }
  }

  // ---- gold path score (one t per thread)
  float g = 0.0f;
  if (tid < len) {
    const int cur = tags[b * TT + tid];
    const int prev = (tid == 0) ? START_IDX : tags[b * TT + tid - 1];
    g = trans[cur * NN + prev] + up[(size_t)tid * NN + cur];
  }
#pragma unroll
  for (int k = 32; k >= 1; k >>= 1) g += __shfl_xor(g, k, 64);
  if (lane == 0) red[wave] = g;
  __syncthreads();
  if (tid == 0) {
    const int lt = tags[b * TT + len - 1];
    float gs = red[0];
#pragma unroll
    for (int w = 1; w < 8; ++w) gs += red[w];
    goldS = gs + trans[END_IDX * NN + lt];
  }

  // ---- epilogue ownership: lane c<3 -> row 3*jg+c; wave7 c==3 -> row 136+jg
  const bool erow = (c < 3) || (W7 && (c == 3));
  const int jrow = (c < 3) ? (3 * jg + c) : (136 + jg);
  const int wh = (jrow / QI) * CH + (jrow % QI); // fp16 write slot

  // u pipeline: loads 3 ahead, exp 1 ahead
  float uexpC = 0.f, uA = 0.f, uB = 0.f;
  if (erow) {
    uexpC = __expf(up[jrow]);
    uA = up[(size_t)((1 < len) ? 1 : len - 1) * NN + jrow];
    uB = up[(size_t)((2 < len) ? 2 : len - 1) * NN + jrow];
  }
  float A = 0.0f; // running scale
  __syncthreads();

  // ---- main scan: one barrier per step
  for (int t = 0; t < len; ++t) {
    const int rb = t & 1, wb = rb ^ 1;

    // issue early: scale array + p chunk (latency hides under issue phase)
    const float4 w0 = *reinterpret_cast<const float4*>(&whm[rb][0]);
    const float4 w1 = *reinterpret_cast<const float4*>(&whm[rb][4]);
    const _Float16* pc = &pH[rb][c * CH];
    const uint4 q0 = reinterpret_cast<const uint4*>(pc)[0];
    const uint4 q1 = reinterpret_cast<const uint4*>(pc)[1];
    const uint4 q2 = reinterpret_cast<const uint4*>(pc)[2];
    const uint2 q3 = reinterpret_cast<const uint2*>(pc)[6];
    const uint pw[14] = {q0.x, q0.y, q0.z, q0.w, q1.x, q1.y, q1.z, q1.w,
                         q2.x, q2.y, q2.z, q2.w, q3.x, q3.y};

    // off-path: M, 1/M, A (feeds pnew late)
    const float M = max8f(w0, w1);
    const float rcpM = __builtin_amdgcn_rcpf(M);
    A += __logf(M);

    // off-path: u pipeline
    float L = 0.f;
    if (erow) {
      const int ti = (t + 3 < len) ? (t + 3) : (len - 1);
      L = up[(size_t)ti * NN + jrow];
    }
    const float uexpN = erow ? __expf(uA) : 0.f;
    const float f = uexpC * rcpM;

    // critical path: S = E * p via fp16 dot2, fp32 accumulate
    float a0 = 0.f, a1 = 0.f, a2 = 0.f, aX = 0.f;
#pragma unroll
    for (int k = 0; k < QI / 2; ++k) {
      const v2h pk = __builtin_bit_cast(v2h, pw[k]);
      a0 = fdot2(Er[0][k], pk, a0);
      a1 = fdot2(Er[1][k], pk, a1);
      a2 = fdot2(Er[2][k], pk, a2);
      if (W7) aX = fdot2(Ex[k], pk, aX);
    }
    const float s0 = dpp_add8(a0);
    const float s1 = dpp_add8(a1);
    const float s2 = dpp_add8(a2);
    float s = s0;
    s = (c == 1) ? s1 : s;
    s = (c == 2) ? s2 : s;
    if (W7) {
      const float sX = dpp_add8(aX);
      s = (c == 3) ? sX : s;
    }

    const float pnew = s * f; // S * exp(u) / M
    float mx = erow ? pnew : 0.f;
    mx = wave_max_dpp(mx); // lane 63 valid
    if (erow) pH[wb][wh] = (_Float16)pnew;
    if (lane == 63) whm[wb][wave] = mx;

    uexpC = uexpN; uA = uB; uB = L;
    __syncthreads();
  }

  // ---- terminal: alpha = A + log(p); logsumexp_j(alpha + trans[END,j])
  const int fb = len & 1;
  float v = -3e38f;
  if (tid < NN) {
    const float pv = (float)pH[fb][(tid / QI) * CH + (tid % QI)];
    const float lp = (pv > 0.f) ? __logf(pv) : -1e30f;
    v = A + lp + trans[END_IDX * NN + tid];
  }
  float mm = v;
#pragma unroll
  for (int k = 32; k >= 1; k >>= 1) mm = fmaxf(mm, __shfl_xor(mm, k, 64));
  if (lane == 0) red[wave] = mm;
  __syncthreads();
  mm = red[0];
#pragma unroll
  for (int w = 1; w < 8; ++w) mm = fmaxf(mm, red[w]);
  float e = (tid < NN) ? __expf(v - mm) : 0.0f;
#pragma unroll
  for (int k = 32; k >= 1; k >>= 1) e += __shfl_xor(e, k, 64);
  if (lane == 0) redE[wave] = e;
  __syncthreads();
  if (tid == 0) {
    float es = redE[0];
#pragma unroll
    for (int w = 1; w < 8; ++w) es += redE[w];
    ws[b] = (mm + __logf(es)) - goldS;
  }
}

__global__ void crf_reduce_kernel(const float* __restrict__ wsIn,
                                  float* __restrict__ out) {
  const int tid = threadIdx.x; // 128 threads
  float v = wsIn[tid];
#pragma unroll
  for (int k = 32; k >= 1; k >>= 1) v += __shfl_xor(v, k, 64);
  __shared__ float s2[2];
  if ((tid & 63) == 0) s2[tid >> 6] = v;
  __syncthreads();
  if (tid == 0) out[0] = (s2[0] + s2[1]) * (1.0f / 128.0f);
}

extern "C" void kernel_launch(void* const* d_in, const int* in_sizes, int n_in,
                              void* d_out, int out_size, void* d_ws, size_t ws_size,
                              hipStream_t stream) {
  const float* unary = (const float*)d_in[0];
  const int* tags = (const int*)d_in[1];
  const int* lengths = (const int*)d_in[2];
  const float* trans = (const float*)d_in[3];
  float* ws = (float*)d_ws;
  float* out = (float*)d_out;

  crf_fwd_kernel<<<BB, NT, 0, stream>>>(unary, tags, lengths, trans, ws);
  crf_reduce_kernel<<<1, 128, 0, stream>>>(ws, out);
}

// Round 6
// 316.490 us; speedup vs baseline: 2.1304x; 1.0342x over previous
//
#include <hip/hip_runtime.h>

typedef _Float16 v2h __attribute__((ext_vector_type(2)));

#define BB 128
#define TT 512
#define NN 200
#define START_IDX 1
#define END_IDX 2

#define NT 512        // 8 waves
#define QI 28         // valid halves per chunk (chunk owner c = lane&7)
#define CH 40         // padded halves per chunk: 80B stride -> 16B aligned, conflict-free banks
#define PSLOTS (8*CH) // 320

__device__ __forceinline__ float fdot2(v2h a, v2h b, float c) {
  return __builtin_amdgcn_fdot2(a, b, c, false);
}

// sum over 8-lane group; all 8 lanes get the sum
__device__ __forceinline__ float dpp_add8(float x) {
  int v;
  v = __builtin_amdgcn_mov_dpp(__float_as_int(x), 0xB1, 0xF, 0xF, true);  // quad xor1
  x += __int_as_float(v);
  v = __builtin_amdgcn_mov_dpp(__float_as_int(x), 0x4E, 0xF, 0xF, true);  // quad xor2
  x += __int_as_float(v);
  v = __builtin_amdgcn_mov_dpp(__float_as_int(x), 0x141, 0xF, 0xF, true); // row_half_mirror
  x += __int_as_float(v);
  return x;
}

// full-wave sum, pure DPP; result valid in lanes 48-63 (use lane 63)
__device__ __forceinline__ float wave_sum_dpp(float x) {
  int v;
  v = __builtin_amdgcn_mov_dpp(__float_as_int(x), 0xB1, 0xF, 0xF, true);
  x += __int_as_float(v);
  v = __builtin_amdgcn_mov_dpp(__float_as_int(x), 0x4E, 0xF, 0xF, true);
  x += __int_as_float(v);
  v = __builtin_amdgcn_mov_dpp(__float_as_int(x), 0x141, 0xF, 0xF, true);
  x += __int_as_float(v);
  v = __builtin_amdgcn_mov_dpp(__float_as_int(x), 0x140, 0xF, 0xF, true); // row_mirror
  x += __int_as_float(v);
  v = __builtin_amdgcn_mov_dpp(__float_as_int(x), 0x142, 0xF, 0xF, true); // bcast15
  x += __int_as_float(v);
  v = __builtin_amdgcn_mov_dpp(__float_as_int(x), 0x143, 0xF, 0xF, true); // bcast31
  x += __int_as_float(v);
  return x;
}

// full-wave max (nonneg inputs), pure DPP; result valid in lane 63
__device__ __forceinline__ float wave_max_dpp(float x) {
  int v;
  v = __builtin_amdgcn_mov_dpp(__float_as_int(x), 0xB1, 0xF, 0xF, true);
  x = fmaxf(x, __int_as_float(v));
  v = __builtin_amdgcn_mov_dpp(__float_as_int(x), 0x4E, 0xF, 0xF, true);
  x = fmaxf(x, __int_as_float(v));
  v = __builtin_amdgcn_mov_dpp(__float_as_int(x), 0x141, 0xF, 0xF, true);
  x = fmaxf(x, __int_as_float(v));
  v = __builtin_amdgcn_mov_dpp(__float_as_int(x), 0x140, 0xF, 0xF, true);
  x = fmaxf(x, __int_as_float(v));
  v = __builtin_amdgcn_mov_dpp(__float_as_int(x), 0x142, 0xF, 0xF, true);
  x = fmaxf(x, __int_as_float(v));
  v = __builtin_amdgcn_mov_dpp(__float_as_int(x), 0x143, 0xF, 0xF, true);
  x = fmaxf(x, __int_as_float(v));
  return x;
}

__device__ __forceinline__ float max8f(float4 a, float4 b) {
  return fmaxf(fmaxf(fmaxf(a.x, a.y), fmaxf(a.z, a.w)),
               fmaxf(fmaxf(b.x, b.y), fmaxf(b.z, b.w)));
}

__global__ __attribute__((amdgpu_flat_work_group_size(NT, NT),
                          amdgpu_waves_per_eu(2, 2)))
void crf_fwd_kernel(
    const float* __restrict__ unary, const int* __restrict__ tags,
    const int* __restrict__ lengths, const float* __restrict__ trans,
    float* __restrict__ ws) {
  const int b = blockIdx.x;
  const int tid = threadIdx.x;
  const int lane = tid & 63;
  const int wave = tid >> 6;
  const int c = lane & 7;          // i-chunk: i in [28c, 28c+28)
  const int g = (lane >> 3) & 7;   // local group within wave
  const int jg = (wave << 3) + g;  // global group id [0,64)
  const int len = lengths[b];

  __shared__ __align__(16) _Float16 pH[2][PSLOTS]; // p in fp16, 80B chunk stride
  __shared__ __align__(16) float whm[2][8];
  // Occupancy pin: 92KB forces 1 block/CU (allocator then budgets VGPRs for
  // 2 waves/EU; also guarantees the 128 blocks land on 128 distinct CUs).
  // big[0..7]=red, big[8..15]=redE, big[16]=goldS.
  __shared__ __align__(16) float big[23040];

  const float* up = unary + (size_t)b * (TT * NN);

  // ---- init: p0 = 1 at START (chunk 0 slot 1), 0 elsewhere; pads stay 0
  if (tid < PSLOTS) {
    pH[0][tid] = (tid == START_IDX) ? (_Float16)1.0f : (_Float16)0.0f;
    pH[1][tid] = (_Float16)0.0f;
  }
  if (tid < 8) { whm[0][tid] = 1.0f; whm[1][tid] = 0.0f; } // max(p0)=1
  if (len < 0) big[23039] = 0.f; // never true; keeps the pad array alive

  // ---- E = exp(trans) fp16: group jg owns rows 3*jg+r (r<3) -> rows 0..191
  v2h Er[3][QI / 2];
#pragma unroll
  for (int r = 0; r < 3; ++r) {
    const int j = 3 * jg + r; // < 192 always
    if (c < 7) {
      const float4* t4 = reinterpret_cast<const float4*>(trans + j * NN + c * QI);
#pragma unroll
      for (int k = 0; k < 7; ++k) {
        const float4 tv = t4[k];
        Er[r][2 * k + 0] = v2h{(_Float16)__expf(tv.x), (_Float16)__expf(tv.y)};
        Er[r][2 * k + 1] = v2h{(_Float16)__expf(tv.z), (_Float16)__expf(tv.w)};
      }
    } else { // only i = 196..199 valid
      const float4 tv = *reinterpret_cast<const float4*>(trans + j * NN + 196);
      Er[r][0] = v2h{(_Float16)__expf(tv.x), (_Float16)__expf(tv.y)};
      Er[r][1] = v2h{(_Float16)__expf(tv.z), (_Float16)__expf(tv.w)};
#pragma unroll
      for (int k = 2; k < QI / 2; ++k) Er[r][k] = v2h{(_Float16)0, (_Float16)0};
    }
  }
  // ---- extra row jx = 192+wave, distributed over the whole wave:
  //      lane (c,g) covers columns i = 28c + 4g .. +3 (g<7)
  const int jx = 192 + wave;
  v2h ExA = v2h{(_Float16)0, (_Float16)0}, ExB = v2h{(_Float16)0, (_Float16)0};
  if (g < 7 && (c < 7 || g == 0)) { // c==7 only i=196..199 valid (g==0)
    const float4 tv = *reinterpret_cast<const float4*>(trans + jx * NN + c * QI + 4 * g);
    ExA = v2h{(_Float16)__expf(tv.x), (_Float16)__expf(tv.y)};
    ExB = v2h{(_Float16)__expf(tv.z), (_Float16)__expf(tv.w)};
  }

  // ---- gold path score (one t per thread)
  float gacc = 0.0f;
  if (tid < len) {
    const int cur = tags[b * TT + tid];
    const int prev = (tid == 0) ? START_IDX : tags[b * TT + tid - 1];
    gacc = trans[cur * NN + prev] + up[(size_t)tid * NN + cur];
  }
#pragma unroll
  for (int k = 32; k >= 1; k >>= 1) gacc += __shfl_xor(gacc, k, 64);
  if (lane == 0) big[wave] = gacc;
  __syncthreads();
  if (tid == 0) {
    const int lt = tags[b * TT + len - 1];
    float gs = big[0];
#pragma unroll
    for (int w = 1; w < 8; ++w) gs += big[w];
    big[16] = gs + trans[END_IDX * NN + lt];
  }

  // ---- epilogue ownership: lanes c<3 -> row 3*jg+c; lane 63 -> row 192+wave
  const bool erow = (c < 3) || (lane == 63);
  const int jrow = (lane == 63) ? jx : (3 * jg + c);
  const int wh = (jrow / QI) * CH + (jrow % QI);

  // u pipeline: load 2 ahead, exp 1 ahead
  float uexpC = 0.f, uN = 0.f;
  if (erow) {
    uexpC = __expf(up[jrow]);
    uN = up[(size_t)NN + jrow]; // u_1 (len >= 256 always)
  }
  float A = 0.0f; // running scale: alpha = A + log(p)
  __syncthreads();

  // ---- main scan: one barrier per step
  for (int t = 0; t < len; ++t) {
    const int rb = t & 1, wb = rb ^ 1;

    // issue LDS reads early
    const float4 w0 = *reinterpret_cast<const float4*>(&whm[rb][0]);
    const float4 w1 = *reinterpret_cast<const float4*>(&whm[rb][4]);
    const _Float16* pc = &pH[rb][c * CH];
    const uint4 q0 = reinterpret_cast<const uint4*>(pc)[0];
    const uint4 q1 = reinterpret_cast<const uint4*>(pc)[1];
    const uint4 q2 = reinterpret_cast<const uint4*>(pc)[2];
    const uint2 q3 = reinterpret_cast<const uint2*>(pc)[6];
    const uint2 qx = *reinterpret_cast<const uint2*>(&pH[rb][c * CH + 4 * g]);

    // off-path: M, 1/M, A
    const float M = max8f(w0, w1);
    const float rcpM = __builtin_amdgcn_rcpf(M);
    A += __logf(M);

    // off-path: u pipeline
    float L = 0.f;
    if (erow) {
      const int ti = (t + 2 < len) ? (t + 2) : (len - 1);
      L = up[(size_t)ti * NN + jrow];
    }
    const float uexpN = erow ? __expf(uN) : 0.f;
    const float f = uexpC * rcpM;

    // critical path: S = E * p (fp16 dot2, fp32 accumulate)
    const unsigned pw[14] = {q0.x, q0.y, q0.z, q0.w, q1.x, q1.y, q1.z, q1.w,
                             q2.x, q2.y, q2.z, q2.w, q3.x, q3.y};
    float a0 = 0.f, a1 = 0.f, a2 = 0.f;
#pragma unroll
    for (int k = 0; k < QI / 2; ++k) {
      const v2h pk = __builtin_bit_cast(v2h, pw[k]);
      a0 = fdot2(Er[0][k], pk, a0);
      a1 = fdot2(Er[1][k], pk, a1);
      a2 = fdot2(Er[2][k], pk, a2);
    }
    float ax = fdot2(ExA, __builtin_bit_cast(v2h, qx.x), 0.f);
    ax = fdot2(ExB, __builtin_bit_cast(v2h, qx.y), ax);

    const float s0 = dpp_add8(a0);
    const float s1 = dpp_add8(a1);
    const float s2 = dpp_add8(a2);
    const float sx = wave_sum_dpp(ax); // lane 63 valid
    float s = s0;
    s = (c == 1) ? s1 : s;
    s = (c == 2) ? s2 : s;
    s = (lane == 63) ? sx : s;

    const float pnew = s * f; // S * exp(u) / M
    // whm tracks rows 0..191 only (extra rows excluded: drift <= e^8, fp16-safe)
    const float mi = (erow && lane != 63) ? pnew : 0.f;
    const float mx = wave_max_dpp(mi); // lane 63 valid
    if (erow) pH[wb][wh] = (_Float16)pnew;
    if (lane == 63) whm[wb][wave] = mx;

    uexpC = uexpN; uN = L;
    __syncthreads();
  }

  // ---- terminal: alpha = A + log(p); logsumexp_j(alpha + trans[END,j])
  const int fb = len & 1;
  float v = -3e38f;
  if (tid < NN) {
    const float pv = (float)pH[fb][(tid / QI) * CH + (tid % QI)];
    const float lp = (pv > 0.f) ? __logf(pv) : -1e30f;
    v = A + lp + trans[END_IDX * NN + tid];
  }
  float mm = v;
#pragma unroll
  for (int k = 32; k >= 1; k >>= 1) mm = fmaxf(mm, __shfl_xor(mm, k, 64));
  if (lane == 0) big[wave] = mm;
  __syncthreads();
  mm = big[0];
#pragma unroll
  for (int w = 1; w < 8; ++w) mm = fmaxf(mm, big[w]);
  float e = (tid < NN) ? __expf(v - mm) : 0.0f;
#pragma unroll
  for (int k = 32; k >= 1; k >>= 1) e += __shfl_xor(e, k, 64);
  if (lane == 0) big[8 + wave] = e;
  __syncthreads();
  if (tid == 0) {
    float es = big[8];
#pragma unroll
    for (int w = 1; w < 8; ++w) es += big[8 + w];
    ws[b] = (mm + __logf(es)) - big[16];
  }
}

__global__ void crf_reduce_kernel(const float* __restrict__ wsIn,
                                  float* __restrict__ out) {
  const int tid = threadIdx.x; // 128 threads
  float v = wsIn[tid];
#pragma unroll
  for (int k = 32; k >= 1; k >>= 1) v += __shfl_xor(v, k, 64);
  __shared__ float s2[2];
  if ((tid & 63) == 0) s2[tid >> 6] = v;
  __syncthreads();
  if (tid == 0) out[0] = (s2[0] + s2[1]) * (1.0f / 128.0f);
}

extern "C" void kernel_launch(void* const* d_in, const int* in_sizes, int n_in,
                              void* d_out, int out_size, void* d_ws, size_t ws_size,
                              hipStream_t stream) {
  const float* unary = (const float*)d_in[0];
  const int* tags = (const int*)d_in[1];
  const int* lengths = (const int*)d_in[2];
  const float* trans = (const float*)d_in[3];
  float* ws = (float*)d_ws;
  float* out = (float*)d_out;

  crf_fwd_kernel<<<BB, NT, 0, stream>>>(unary, tags, lengths, trans, ws);
  crf_reduce_kernel<<<1, 128, 0, stream>>>(ws, out);
}

// Round 7
// 313.310 us; speedup vs baseline: 2.1521x; 1.0101x over previous
//
#include <hip/hip_runtime.h>

typedef _Float16 v2h __attribute__((ext_vector_type(2)));

#define BB 128
#define TT 512
#define NN 200
#define START_IDX 1
#define END_IDX 2

#define NT 512        // 8 waves
#define QI 28         // valid halves per chunk (chunk owner c = lane&7)
#define CH 40         // padded halves per chunk: 80B stride -> 16B aligned, conflict-free banks
#define PSLOTS (8*CH) // 320

__device__ __forceinline__ float fdot2(v2h a, v2h b, float c) {
  return __builtin_amdgcn_fdot2(a, b, c, false);
}

// LDS-only barrier: does NOT drain vmcnt, so global u-prefetch loads stay in
// flight across steps (plain __syncthreads emits s_waitcnt vmcnt(0) and
// serializes ~200-900cyc of L2/HBM latency onto every step's barrier).
__device__ __forceinline__ void sync_lds() {
  asm volatile("s_waitcnt lgkmcnt(0)" ::: "memory"); // my LDS writes complete
  __builtin_amdgcn_s_barrier();
  __builtin_amdgcn_sched_barrier(0); // rule #18: keep next step's ds_reads after barrier
}

// sum over 8-lane group; all 8 lanes get the sum
__device__ __forceinline__ float dpp_add8(float x) {
  int v;
  v = __builtin_amdgcn_mov_dpp(__float_as_int(x), 0xB1, 0xF, 0xF, true);  // quad xor1
  x += __int_as_float(v);
  v = __builtin_amdgcn_mov_dpp(__float_as_int(x), 0x4E, 0xF, 0xF, true);  // quad xor2
  x += __int_as_float(v);
  v = __builtin_amdgcn_mov_dpp(__float_as_int(x), 0x141, 0xF, 0xF, true); // row_half_mirror
  x += __int_as_float(v);
  return x;
}

// full-wave sum, pure DPP; result valid in lane 63
__device__ __forceinline__ float wave_sum_dpp(float x) {
  int v;
  v = __builtin_amdgcn_mov_dpp(__float_as_int(x), 0xB1, 0xF, 0xF, true);
  x += __int_as_float(v);
  v = __builtin_amdgcn_mov_dpp(__float_as_int(x), 0x4E, 0xF, 0xF, true);
  x += __int_as_float(v);
  v = __builtin_amdgcn_mov_dpp(__float_as_int(x), 0x141, 0xF, 0xF, true);
  x += __int_as_float(v);
  v = __builtin_amdgcn_mov_dpp(__float_as_int(x), 0x140, 0xF, 0xF, true); // row_mirror
  x += __int_as_float(v);
  v = __builtin_amdgcn_mov_dpp(__float_as_int(x), 0x142, 0xF, 0xF, true); // bcast15
  x += __int_as_float(v);
  v = __builtin_amdgcn_mov_dpp(__float_as_int(x), 0x143, 0xF, 0xF, true); // bcast31
  x += __int_as_float(v);
  return x;
}

// full-wave max (nonneg inputs), pure DPP; result valid in lane 63
__device__ __forceinline__ float wave_max_dpp(float x) {
  int v;
  v = __builtin_amdgcn_mov_dpp(__float_as_int(x), 0xB1, 0xF, 0xF, true);
  x = fmaxf(x, __int_as_float(v));
  v = __builtin_amdgcn_mov_dpp(__float_as_int(x), 0x4E, 0xF, 0xF, true);
  x = fmaxf(x, __int_as_float(v));
  v = __builtin_amdgcn_mov_dpp(__float_as_int(x), 0x141, 0xF, 0xF, true);
  x = fmaxf(x, __int_as_float(v));
  v = __builtin_amdgcn_mov_dpp(__float_as_int(x), 0x140, 0xF, 0xF, true);
  x = fmaxf(x, __int_as_float(v));
  v = __builtin_amdgcn_mov_dpp(__float_as_int(x), 0x142, 0xF, 0xF, true);
  x = fmaxf(x, __int_as_float(v));
  v = __builtin_amdgcn_mov_dpp(__float_as_int(x), 0x143, 0xF, 0xF, true);
  x = fmaxf(x, __int_as_float(v));
  return x;
}

__device__ __forceinline__ float max8f(float4 a, float4 b) {
  return fmaxf(fmaxf(fmaxf(a.x, a.y), fmaxf(a.z, a.w)),
               fmaxf(fmaxf(b.x, b.y), fmaxf(b.z, b.w)));
}

__global__ __attribute__((amdgpu_flat_work_group_size(NT, NT),
                          amdgpu_waves_per_eu(2, 2)))
void crf_fwd_kernel(
    const float* __restrict__ unary, const int* __restrict__ tags,
    const int* __restrict__ lengths, const float* __restrict__ trans,
    float* __restrict__ ws) {
  const int b = blockIdx.x;
  const int tid = threadIdx.x;
  const int lane = tid & 63;
  const int wave = tid >> 6;
  const int c = lane & 7;          // i-chunk: i in [28c, 28c+28)
  const int g = (lane >> 3) & 7;   // local group within wave
  const int jg = (wave << 3) + g;  // global group id [0,64)
  const int len = lengths[b];

  __shared__ __align__(16) _Float16 pH[2][PSLOTS]; // p in fp16, 80B chunk stride
  __shared__ __align__(16) float whm[2][8];
  // Occupancy pin: 92KB forces 1 block/CU (128 blocks -> 128 distinct CUs).
  // big[0..7]=red, big[8..15]=redE, big[16]=goldS.
  __shared__ __align__(16) float big[23040];

  const float* up = unary + (size_t)b * (TT * NN);

  // ---- init: p0 = 1 at START (chunk 0 slot 1), 0 elsewhere; pads stay 0
  if (tid < PSLOTS) {
    pH[0][tid] = (tid == START_IDX) ? (_Float16)1.0f : (_Float16)0.0f;
    pH[1][tid] = (_Float16)0.0f;
  }
  if (tid < 8) { whm[0][tid] = 1.0f; whm[1][tid] = 0.0f; } // max(p0)=1
  if (len < 0) big[23039] = 0.f; // never true; keeps the pad array alive

  // ---- E = exp(trans) fp16: group jg owns rows 3*jg+r (r<3) -> rows 0..191
  v2h Er[3][QI / 2];
#pragma unroll
  for (int r = 0; r < 3; ++r) {
    const int j = 3 * jg + r; // < 192 always
    if (c < 7) {
      const float4* t4 = reinterpret_cast<const float4*>(trans + j * NN + c * QI);
#pragma unroll
      for (int k = 0; k < 7; ++k) {
        const float4 tv = t4[k];
        Er[r][2 * k + 0] = v2h{(_Float16)__expf(tv.x), (_Float16)__expf(tv.y)};
        Er[r][2 * k + 1] = v2h{(_Float16)__expf(tv.z), (_Float16)__expf(tv.w)};
      }
    } else { // only i = 196..199 valid
      const float4 tv = *reinterpret_cast<const float4*>(trans + j * NN + 196);
      Er[r][0] = v2h{(_Float16)__expf(tv.x), (_Float16)__expf(tv.y)};
      Er[r][1] = v2h{(_Float16)__expf(tv.z), (_Float16)__expf(tv.w)};
#pragma unroll
      for (int k = 2; k < QI / 2; ++k) Er[r][k] = v2h{(_Float16)0, (_Float16)0};
    }
  }
  // ---- extra row jx = 192+wave, distributed over the whole wave:
  //      lane (c,g) covers columns i = 28c + 4g .. +3 (g<7)
  const int jx = 192 + wave;
  v2h ExA = v2h{(_Float16)0, (_Float16)0}, ExB = v2h{(_Float16)0, (_Float16)0};
  if (g < 7 && (c < 7 || g == 0)) { // c==7 only i=196..199 valid (g==0)
    const float4 tv = *reinterpret_cast<const float4*>(trans + jx * NN + c * QI + 4 * g);
    ExA = v2h{(_Float16)__expf(tv.x), (_Float16)__expf(tv.y)};
    ExB = v2h{(_Float16)__expf(tv.z), (_Float16)__expf(tv.w)};
  }

  // ---- gold path score (one t per thread)
  float gacc = 0.0f;
  if (tid < len) {
    const int cur = tags[b * TT + tid];
    const int prev = (tid == 0) ? START_IDX : tags[b * TT + tid - 1];
    gacc = trans[cur * NN + prev] + up[(size_t)tid * NN + cur];
  }
#pragma unroll
  for (int k = 32; k >= 1; k >>= 1) gacc += __shfl_xor(gacc, k, 64);
  if (lane == 0) big[wave] = gacc;
  __syncthreads();
  if (tid == 0) {
    const int lt = tags[b * TT + len - 1];
    float gs = big[0];
#pragma unroll
    for (int w = 1; w < 8; ++w) gs += big[w];
    big[16] = gs + trans[END_IDX * NN + lt];
  }

  // ---- epilogue ownership: lanes c<3 -> row 3*jg+c; lane 63 -> row 192+wave
  const bool erow = (c < 3) || (lane == 63);
  const int jrow = (lane == 63) ? jx : (3 * jg + c);
  const int wh = (jrow / QI) * CH + (jrow % QI);

  // u pipeline: load 2 ahead, exp 1 ahead
  float uexpC = 0.f, uN = 0.f;
  if (erow) {
    uexpC = __expf(up[jrow]);
    uN = up[(size_t)NN + jrow]; // u_1 (len >= 256 always)
  }
  float A = 0.0f; // running scale: alpha = A + log(p)
  __syncthreads();

  // ---- main scan: one LDS-only barrier per step
  for (int t = 0; t < len; ++t) {
    const int rb = t & 1, wb = rb ^ 1;

    // issue LDS reads early
    const float4 w0 = *reinterpret_cast<const float4*>(&whm[rb][0]);
    const float4 w1 = *reinterpret_cast<const float4*>(&whm[rb][4]);
    const _Float16* pc = &pH[rb][c * CH];
    const uint4 q0 = reinterpret_cast<const uint4*>(pc)[0];
    const uint4 q1 = reinterpret_cast<const uint4*>(pc)[1];
    const uint4 q2 = reinterpret_cast<const uint4*>(pc)[2];
    const uint2 q3 = reinterpret_cast<const uint2*>(pc)[6];
    const uint2 qx = *reinterpret_cast<const uint2*>(&pH[rb][c * CH + 4 * g]);

    // off-path: M, 1/M, A
    const float M = max8f(w0, w1);
    const float rcpM = __builtin_amdgcn_rcpf(M);
    A += __logf(M);

    // off-path: u pipeline (global load stays in flight across the barrier now)
    float L = 0.f;
    if (erow) {
      const int ti = (t + 2 < len) ? (t + 2) : (len - 1);
      L = up[(size_t)ti * NN + jrow];
    }
    const float uexpN = erow ? __expf(uN) : 0.f;
    const float f = uexpC * rcpM;

    // critical path: S = E * p (fp16 dot2, fp32 accumulate)
    const unsigned pw[14] = {q0.x, q0.y, q0.z, q0.w, q1.x, q1.y, q1.z, q1.w,
                             q2.x, q2.y, q2.z, q2.w, q3.x, q3.y};
    float a0 = 0.f, a1 = 0.f, a2 = 0.f;
#pragma unroll
    for (int k = 0; k < QI / 2; ++k) {
      const v2h pk = __builtin_bit_cast(v2h, pw[k]);
      a0 = fdot2(Er[0][k], pk, a0);
      a1 = fdot2(Er[1][k], pk, a1);
      a2 = fdot2(Er[2][k], pk, a2);
    }
    float ax = fdot2(ExA, __builtin_bit_cast(v2h, qx.x), 0.f);
    ax = fdot2(ExB, __builtin_bit_cast(v2h, qx.y), ax);

    const float s0 = dpp_add8(a0);
    const float s1 = dpp_add8(a1);
    const float s2 = dpp_add8(a2);
    const float sx = wave_sum_dpp(ax); // lane 63 valid
    float s = s0;
    s = (c == 1) ? s1 : s;
    s = (c == 2) ? s2 : s;
    s = (lane == 63) ? sx : s;

    const float pnew = s * f; // S * exp(u) / M
    if (erow) pH[wb][wh] = (_Float16)pnew; // write early: overlaps wave_max chain
    // whm tracks rows 0..191 only (extra rows excluded: drift <= e^8, fp16-safe)
    const float mi = (erow && lane != 63) ? pnew : 0.f;
    const float mx = wave_max_dpp(mi); // lane 63 valid
    if (lane == 63) whm[wb][wave] = mx;

    uexpC = uexpN; uN = L;
    sync_lds();
  }

  // ---- terminal: alpha = A + log(p); logsumexp_j(alpha + trans[END,j])
  const int fb = len & 1;
  float v = -3e38f;
  if (tid < NN) {
    const float pv = (float)pH[fb][(tid / QI) * CH + (tid % QI)];
    const float lp = (pv > 0.f) ? __logf(pv) : -1e30f;
    v = A + lp + trans[END_IDX * NN + tid];
  }
  float mm = v;
#pragma unroll
  for (int k = 32; k >= 1; k >>= 1) mm = fmaxf(mm, __shfl_xor(mm, k, 64));
  if (lane == 0) big[wave] = mm;
  __syncthreads();
  mm = big[0];
#pragma unroll
  for (int w = 1; w < 8; ++w) mm = fmaxf(mm, big[w]);
  float e = (tid < NN) ? __expf(v - mm) : 0.0f;
#pragma unroll
  for (int k = 32; k >= 1; k >>= 1) e += __shfl_xor(e, k, 64);
  if (lane == 0) big[8 + wave] = e;
  __syncthreads();
  if (tid == 0) {
    float es = big[8];
#pragma unroll
    for (int w = 1; w < 8; ++w) es += big[8 + w];
    ws[b] = (mm + __logf(es)) - big[16];
  }
}

__global__ void crf_reduce_kernel(const float* __restrict__ wsIn,
                                  float* __restrict__ out) {
  const int tid = threadIdx.x; // 128 threads
  float v = wsIn[tid];
#pragma unroll
  for (int k = 32; k >= 1; k >>= 1) v += __shfl_xor(v, k, 64);
  __shared__ float s2[2];
  if ((tid & 63) == 0) s2[tid >> 6] = v;
  __syncthreads();
  if (tid == 0) out[0] = (s2[0] + s2[1]) * (1.0f / 128.0f);
}

extern "C" void kernel_launch(void* const* d_in, const int* in_sizes, int n_in,
                              void* d_out, int out_size, void* d_ws, size_t ws_size,
                              hipStream_t stream) {
  const float* unary = (const float*)d_in[0];
  const int* tags = (const int*)d_in[1];
  const int* lengths = (const int*)d_in[2];
  const float* trans = (const float*)d_in[3];
  float* ws = (float*)d_ws;
  float* out = (float*)d_out;

  crf_fwd_kernel<<<BB, NT, 0, stream>>>(unary, tags, lengths, trans, ws);
  crf_reduce_kernel<<<1, 128, 0, stream>>>(ws, out);
}